// Round 7
// baseline (137.715 us; speedup 1.0000x reference)
//
#include <hip/hip_runtime.h>

// BPMLL loss, B=16384 rows, L=1024 cols, f32 in, scalar f32 out.
// Per row: pos = sum y*exp(-c); neg = sum (1-y)*exp(c);
// loss = pos*neg/(sum_y*(L-sum_y)); out = mean over rows.
//
// R6 post-mortem: persistent + nt + register double-buffer dropped rows
// kernel below 40.6us (out of top-5; est ~36us, ~3.7 TB/s). Harness fill
// dispatches prove pure-write = 6.5 TB/s -> no per-direction ceiling; reads
// should reach ~5 TB/s (m146: 4.89). R5 capped residency at 8 waves/CU.
// R7 single-variable change: 16 waves/CU (1024 blocks, launch_bounds(256,4),
// 4 rows/wave), same nt double-buffer inner loop. Data VGPRs=64, total ~100.

#define NROWS 16384
#define NCOLS 1024
#define WPB 4
#define NBLOCKS 1024                       // 4 blocks/CU x 4 waves = 16 waves/CU
#define ROWS_PER_WAVE (NROWS / (NBLOCKS * WPB))  // 4

typedef float vf4 __attribute__((ext_vector_type(4)));
typedef int vi4 __attribute__((ext_vector_type(4)));

__device__ __forceinline__ void elem(float cv, int yv,
                                     float& pos, float& neg, float& cnt) {
    float t = __expf(yv ? -cv : cv);   // one transcendental per element
    pos += yv ? t : 0.f;
    neg += yv ? 0.f : t;
    cnt += (float)yv;
}

__device__ __forceinline__ void consume4(const vf4& cv, const vi4& yv,
                                         float& pos, float& neg, float& cnt) {
    elem(cv.x, yv.x, pos, neg, cnt);
    elem(cv.y, yv.y, pos, neg, cnt);
    elem(cv.z, yv.z, pos, neg, cnt);
    elem(cv.w, yv.w, pos, neg, cnt);
}

__device__ __forceinline__ float row_finish(float pos, float neg, float cnt) {
#pragma unroll
    for (int off = 1; off < 64; off <<= 1) {
        pos += __shfl_xor(pos, off);
        neg += __shfl_xor(neg, off);
        cnt += __shfl_xor(cnt, off);
    }
    return (pos * neg) / (cnt * ((float)NCOLS - cnt));  // BIAS=(1,1)
}

__global__ __launch_bounds__(256, 4) void bpmll_rows_kernel(
    const float* __restrict__ c, const int* __restrict__ y,
    float* __restrict__ partials) {
    const int wave = threadIdx.x >> 6;
    const int lane = threadIdx.x & 63;
    const int gw = blockIdx.x * WPB + wave;        // 0..4095
    const int row0 = gw * ROWS_PER_WAVE;           // 4 contiguous rows/wave

    const vf4* __restrict__ cp = (const vf4*)(c + (size_t)row0 * NCOLS);
    const vi4* __restrict__ yp = (const vi4*)(y + (size_t)row0 * NCOLS);
    // row stride = 256 vf4 / vi4

    vf4 cbuf[2][4];
    vi4 ybuf[2][4];

    // Prime the pipeline: row 0 into buffer 0 (nontemporal).
#pragma unroll
    for (int i = 0; i < 4; ++i)
        cbuf[0][i] = __builtin_nontemporal_load(&cp[lane + 64 * i]);
#pragma unroll
    for (int i = 0; i < 4; ++i)
        ybuf[0][i] = __builtin_nontemporal_load(&yp[lane + 64 * i]);

    float wave_loss = 0.f;
#pragma unroll
    for (int r = 0; r < ROWS_PER_WAVE; ++r) {
        const int cur = r & 1, nxt = cur ^ 1;
        if (r < ROWS_PER_WAVE - 1) {  // prefetch next row while consuming
            const vf4* cn = cp + (size_t)(r + 1) * (NCOLS / 4);
            const vi4* yn = yp + (size_t)(r + 1) * (NCOLS / 4);
#pragma unroll
            for (int i = 0; i < 4; ++i)
                cbuf[nxt][i] = __builtin_nontemporal_load(&cn[lane + 64 * i]);
#pragma unroll
            for (int i = 0; i < 4; ++i)
                ybuf[nxt][i] = __builtin_nontemporal_load(&yn[lane + 64 * i]);
        }
        float pos = 0.f, neg = 0.f, cnt = 0.f;
#pragma unroll
        for (int i = 0; i < 4; ++i)
            consume4(cbuf[cur][i], ybuf[cur][i], pos, neg, cnt);
        wave_loss += row_finish(pos, neg, cnt);
    }

    __shared__ float acc[WPB];
    if (lane == 0) acc[wave] = wave_loss;
    __syncthreads();
    if (threadIdx.x == 0) {
        partials[blockIdx.x] =
            (acc[0] + acc[1] + acc[2] + acc[3]) * (1.0f / (float)NROWS);
    }
}

__global__ __launch_bounds__(256) void bpmll_reduce_kernel(
    const float* __restrict__ partials, float* __restrict__ out) {
    // 1024 partials, 256 threads -> one float4 per thread.
    float4 v = ((const float4*)partials)[threadIdx.x];
    float s = v.x + v.y + v.z + v.w;
#pragma unroll
    for (int off = 1; off < 64; off <<= 1) s += __shfl_xor(s, off);

    __shared__ float smem[4];
    const int lane = threadIdx.x & 63;
    const int wave = threadIdx.x >> 6;
    if (lane == 0) smem[wave] = s;
    __syncthreads();
    if (threadIdx.x == 0) out[0] = smem[0] + smem[1] + smem[2] + smem[3];
}

extern "C" void kernel_launch(void* const* d_in, const int* in_sizes, int n_in,
                              void* d_out, int out_size, void* d_ws, size_t ws_size,
                              hipStream_t stream) {
    const float* c = (const float*)d_in[0];
    const int* y = (const int*)d_in[1];
    float* partials = (float*)d_ws;   // NBLOCKS floats = 4 KiB scratch
    float* out = (float*)d_out;

    bpmll_rows_kernel<<<NBLOCKS, 256, 0, stream>>>(c, y, partials);
    bpmll_reduce_kernel<<<1, 256, 0, stream>>>(partials, out);
}